// Round 15
// baseline (726.018 us; speedup 1.0000x reference)
//
#include <hip/hip_runtime.h>
#include <hip/hip_bf16.h>

// LinearFLH: out[m,n] = sx[m]*sw[n]*(x[m,:].w[n,:]) + bias[n]
// M=8192, N=11008, K=4096. All harness buffers FLOAT32 (fp16 ref -> "else
// float" rule). Pipeline: (1) f32->bf16 convert of X,W into d_ws, (2) 256x256
// BK=64 bf16 MFMA GEMM, 8 waves, K-synchronized 2D cluster map (R14), and the
// m201-FAITHFUL PHASE ANATOMY: per phase
//   {reads(pre-certified) ; stage 1 half ; vmcnt ; barrier ; lgkmcnt(0) ;
//    setprio(1) 16 MFMA setprio(0) ; barrier}
// Wait derivation (2 loads/half, in-order retirement): steady vmcnt(4) at
// ph0/ph1/ph3 (certifies B1 / A1 / next-tile A0,B0), none at ph2; newest 4
// loads always in flight. Tail tile peeled: (2,0,-,-).
// R14 postmortem: reads-after-barrier + single-barrier phases left MfmaUtil
// at 48% (4878 cy/iter vs 2483 floor); this ports the verified interleave.

#define M_DIM 8192
#define N_DIM 11008
#define K_DIM 4096
#define BM 256
#define BN 256
#define BK 64
#define NT (K_DIM / BK)                       // 64 K-tiles
#define NWG ((M_DIM / BM) * (N_DIM / BN))     // 32*43 = 1376

#define X_ELEMS (M_DIM * K_DIM)
#define W_ELEMS (N_DIM * K_DIM)
#define WS_NEEDED ((size_t)(X_ELEMS + W_ELEMS) * 2)

typedef __bf16 bf16x8 __attribute__((ext_vector_type(8)));
typedef float f32x4 __attribute__((ext_vector_type(4)));
typedef unsigned short u16x4 __attribute__((ext_vector_type(4)));
typedef unsigned short u16x8 __attribute__((ext_vector_type(8)));

typedef __attribute__((address_space(3))) void lds_void;
typedef const __attribute__((address_space(1))) void gmem_void;

// f32 -> bf16 bits, round-to-nearest-even (inputs finite)
__device__ __forceinline__ unsigned short f2bf(float f) {
    union { float f; unsigned int u; } c; c.f = f;
    unsigned int r = c.u + 0x7FFFu + ((c.u >> 16) & 1u);
    return (unsigned short)(r >> 16);
}

// ---------------- elementwise convert: f32 -> bf16 (proven R8) ----------------
__global__ __launch_bounds__(256) void convert_f32_to_bf16(
    const float* __restrict__ in, unsigned short* __restrict__ out, int n)
{
    int idx = (blockIdx.x * 256 + threadIdx.x) * 8;
    const int stride = gridDim.x * 256 * 8;
    for (; idx < n; idx += stride) {
        const f32x4 a = *(const f32x4*)(in + idx);
        const f32x4 b = *(const f32x4*)(in + idx + 4);
        u16x8 o;
        #pragma unroll
        for (int q = 0; q < 4; ++q) { o[q] = f2bf(a[q]); o[q + 4] = f2bf(b[q]); }
        *(u16x8*)(out + idx) = o;
    }
}

// ---------------- main GEMM: 256x256, 8 waves, m201-style 4-phase ----------------
// LDS: buf c at c*32768 (ushort): A [256][64] at +0 (half h at +h*8192),
// B [256][64] at +16384 (half h at +16384+h*8192).
// T2 swizzle (both sides, rule #21): lds[row][col] = global[row][col ^ ((row&7)<<3)].
__global__ __launch_bounds__(512, 2) void linear_flh_gemm_256(
    const unsigned short* __restrict__ Xb,   // [M,K] bf16 bits (ws)
    const unsigned short* __restrict__ Wb,   // [N,K] bf16 bits (ws)
    const float* __restrict__ SX,            // [M]
    const float* __restrict__ SW,            // [N]
    const float* __restrict__ BIAS,          // [N]
    float* __restrict__ OUT)                 // [M,N] f32
{
    __shared__ unsigned short lds[65536];    // 128 KiB -> 1 workgroup/CU

    const int t    = threadIdx.x;     // 0..511
    const int lane = t & 63;
    const int wid  = t >> 6;          // 0..7
    const int qr   = wid >> 2;        // 0..1: wave-row within 128x128 quadrant
    const int wcol = wid & 3;         // 0..3: wave-col within quadrant
    const int cl   = lane & 15;       // fragment row/col
    const int rl   = lane >> 4;       // 0..3: k-group

    // R14 cluster map (bijective): XCD x owns M-band [4x,4x+4); 32 concurrent
    // CUs = 4x8 MxN patch -> 12 operand slices/K-tile (384 KB) L2-resident.
    const int bid = blockIdx.x;
    const int xcd = bid & 7;
    const int s   = bid >> 3;                 // 0..171
    const int tm  = xcd * 4 + (s & 3);        // 0..31
    const int tn  = s >> 2;                   // 0..42
    const int mBase = tm * BM;
    const int nBase = tn * BN;

    // T2 read-side: element col = (k0) ^ ((row&7)<<3); row&7 == cl&7 below.
    const int colK0 = (rl * 8) ^ ((cl & 7) << 3);
    const int colK1 = colK0 ^ 32;

    f32x4 acc[4][4][2];   // [quadrant mh*2+nh][mi][ni]
    #pragma unroll
    for (int q = 0; q < 4; ++q)
        #pragma unroll
        for (int mi = 0; mi < 4; ++mi)
            #pragma unroll
            for (int ni = 0; ni < 2; ++ni)
                acc[q][mi][ni] = (f32x4){0.f, 0.f, 0.f, 0.f};

    // Stage one 128-row HALF (A or B) = 2 gload_lds(16B)/thread.
    // LDS dest linear (m104); global col pre-swizzled (rule #21).
    #define STAGE_HALF(P_, ROWB_, DSTB_, KCOL_)                                \
        { _Pragma("unroll")                                                    \
          for (int q_ = 0; q_ < 2; ++q_) {                                     \
              const int e_ = q_ * 4096 + t * 8;                                \
              const int r_ = e_ >> 6;                                          \
              const int c_ = ((t & 7) * 8) ^ ((r_ & 7) << 3);                  \
              __builtin_amdgcn_global_load_lds(                                \
                  (gmem_void*)((P_) + (size_t)((ROWB_) + r_) * K_DIM + (KCOL_) + c_),\
                  (lds_void*)(lds + (DSTB_) + e_), 16, 0, 0);                  \
          } }

    #define READ_A(DST_, HB_)                                                  \
        { _Pragma("unroll")                                                    \
          for (int mi_ = 0; mi_ < 4; ++mi_) {                                  \
              const int row_ = qr * 64 + mi_ * 16 + cl;                        \
              DST_[mi_][0] = *(const bf16x8*)(lds + (HB_) + row_ * 64 + colK0);\
              DST_[mi_][1] = *(const bf16x8*)(lds + (HB_) + row_ * 64 + colK1);\
          } }
    #define READ_B(DST_, HB_)                                                  \
        { _Pragma("unroll")                                                    \
          for (int ni_ = 0; ni_ < 2; ++ni_) {                                  \
              const int row_ = wcol * 32 + ni_ * 16 + cl;                      \
              DST_[ni_][0] = *(const bf16x8*)(lds + (HB_) + row_ * 64 + colK0);\
              DST_[ni_][1] = *(const bf16x8*)(lds + (HB_) + row_ * 64 + colK1);\
          } }

    #define MFMA_Q(Q_, AF_, BF_)                                               \
        { __builtin_amdgcn_s_setprio(1);                                       \
          _Pragma("unroll")                                                    \
          for (int mi_ = 0; mi_ < 4; ++mi_)                                    \
              _Pragma("unroll")                                                \
              for (int ni_ = 0; ni_ < 2; ++ni_) {                              \
                  acc[Q_][mi_][ni_] = __builtin_amdgcn_mfma_f32_16x16x32_bf16( \
                      AF_[mi_][0], BF_[ni_][0], acc[Q_][mi_][ni_], 0, 0, 0);   \
                  acc[Q_][mi_][ni_] = __builtin_amdgcn_mfma_f32_16x16x32_bf16( \
                      AF_[mi_][1], BF_[ni_][1], acc[Q_][mi_][ni_], 0, 0, 0);   \
              }                                                                \
          __builtin_amdgcn_s_setprio(0); }

    // m201 phase core: [optional vmcnt] barrier ; lgkmcnt(0) ; MFMA ; barrier
    #define VMC(VM_) asm volatile("s_waitcnt vmcnt(" VM_ ")" ::: "memory");
    #define PHASE_SYNC_MFMA(Q_, AF_, BF_)                                      \
        __builtin_amdgcn_s_barrier();                                          \
        asm volatile("s_waitcnt lgkmcnt(0)" ::: "memory");                     \
        MFMA_Q(Q_, AF_, BF_);                                                  \
        __builtin_amdgcn_s_barrier();

    // Prologue: tile 0 -> buf 0, halves [A0,B0,B1,A1] (8 loads), certify A0,B0.
    STAGE_HALF(Xb, mBase,        0,             0);
    STAGE_HALF(Wb, nBase,        16384,         0);
    STAGE_HALF(Wb, nBase + 128,  16384 + 8192,  0);
    STAGE_HALF(Xb, mBase + 128,  8192,          0);
    VMC("4");                      // newest 4 = B1,A1 -> A0,B0 landed
    __builtin_amdgcn_s_barrier();

    // Steady state: per phase, reads use data certified at the PREVIOUS
    // phase's vmcnt+barrier; vmcnt(4) always leaves the newest 4 loads
    // (the not-yet-needed halves) in flight.
    for (int kt = 0; kt < NT - 1; ++kt) {
        const int cur   = kt & 1;
        const int abase = cur * 32768;
        const int bbase = abase + 16384;
        const int ebase = (cur ^ 1) * 32768;
        const int kn    = (kt + 1) * BK;

        bf16x8 a0[4][2], a1[4][2], b0[2][2], b1[2][2];

        // ph0: q00 = A0 x B0 (A0,B0 certified at loop entry)
        READ_A(a0, abase);
        READ_B(b0, bbase);
        STAGE_HALF(Xb, mBase, ebase, kn);                       // A0'
        VMC("4");                                               // certify B1
        PHASE_SYNC_MFMA(0, a0, b0);

        // ph1: q01 = A0 x B1
        READ_B(b1, bbase + 8192);
        STAGE_HALF(Wb, nBase, ebase + 16384, kn);               // B0'
        VMC("4");                                               // certify A1
        PHASE_SYNC_MFMA(1, a0, b1);

        // ph2: q11 = A1 x B1  (no vmcnt: nothing new needed next phase)
        READ_A(a1, abase + 8192);
        STAGE_HALF(Wb, nBase + 128, ebase + 16384 + 8192, kn);  // B1'
        PHASE_SYNC_MFMA(3, a1, b1);

        // ph3: q10 = A1 x B0 (no reads)
        STAGE_HALF(Xb, mBase + 128, ebase + 8192, kn);          // A1'
        VMC("4");                                               // certify A0',B0'
        PHASE_SYNC_MFMA(2, a1, b0);
    }

    // Tail tile kt = NT-1: no staging -> waits shrink to (2,0,-,-).
    {
        const int abase = ((NT - 1) & 1) * 32768;
        const int bbase = abase + 16384;
        bf16x8 a0[4][2], a1[4][2], b0[2][2], b1[2][2];

        READ_A(a0, abase);
        READ_B(b0, bbase);
        VMC("2");                                 // certify B1 (newer: A1)
        PHASE_SYNC_MFMA(0, a0, b0);

        READ_B(b1, bbase + 8192);
        VMC("0");                                 // certify A1
        PHASE_SYNC_MFMA(1, a0, b1);

        READ_A(a1, abase + 8192);
        PHASE_SYNC_MFMA(3, a1, b1);

        __builtin_amdgcn_s_barrier();
        asm volatile("s_waitcnt lgkmcnt(0)" ::: "memory");
        MFMA_Q(2, a1, b0);
    }

    #undef PHASE_SYNC_MFMA
    #undef VMC
    #undef MFMA_Q
    #undef READ_B
    #undef READ_A
    #undef STAGE_HALF

    // Epilogue: out = acc * sx[row] * sw[col] + bias[col]; NT stores.
    // C/D layout: col = lane&15, row = rl*4 + reg (m89/m91).
    #pragma unroll
    for (int q = 0; q < 4; ++q) {
        const int mh = q >> 1, nh = q & 1;
        #pragma unroll
        for (int mi = 0; mi < 4; ++mi) {
            const int rowb = mBase + mh * 128 + qr * 64 + mi * 16 + rl * 4;
            #pragma unroll
            for (int ni = 0; ni < 2; ++ni) {
                const int col = nBase + nh * 128 + wcol * 32 + ni * 16 + cl;
                const float swv = SW[col];
                const float bv  = BIAS[col];
                #pragma unroll
                for (int rr = 0; rr < 4; ++rr) {
                    const int row = rowb + rr;
                    float v = acc[q][mi][ni][rr] * SX[row] * swv + bv;
                    v = fminf(fmaxf(v, -1.0e5f), 1.0e5f);   // diagnostic sentinel
                    __builtin_nontemporal_store(v, OUT + (size_t)row * N_DIM + col);
                }
            }
        }
    }
}

// ---------------- fallback (R7/R8-proven): inline-convert reg-staged 128^2 ----------------
#define FBM 128
#define FBK 64
__global__ __launch_bounds__(256) void linear_flh_gemm_f32in(
    const float* __restrict__ X, const float* __restrict__ SX,
    const float* __restrict__ W, const float* __restrict__ SW,
    const float* __restrict__ BIAS, float* __restrict__ OUT)
{
    __shared__ alignas(16) unsigned short smA[FBM * FBK];
    __shared__ alignas(16) unsigned short smB[FBM * FBK];
    const int t = threadIdx.x;
    const int lane = t & 63, wave = t >> 6;
    const int wr = wave >> 1, wc = wave & 1;
    int bid = blockIdx.x;
    bid = (bid & 7) * ((M_DIM / FBM) * (N_DIM / FBM) / 8) + (bid >> 3);
    const int mBase = (bid / (N_DIM / FBM)) * FBM;
    const int nBase = (bid % (N_DIM / FBM)) * FBM;
    const int cl = lane & 15, rl = lane >> 4;
    f32x4 acc[4][4];
    #pragma unroll
    for (int i = 0; i < 4; ++i)
        #pragma unroll
        for (int j = 0; j < 4; ++j) acc[i][j] = (f32x4){0.f, 0.f, 0.f, 0.f};
    for (int kt = 0; kt < K_DIM / FBK; ++kt) {
        const int kBase = kt * FBK;
        f32x4 ra[8], rb[8];
        #pragma unroll
        for (int cc = 0; cc < 8; ++cc) {
            const int e = cc * 1024 + t * 4;
            const int r = e >> 6, c = e & 63;
            ra[cc] = *(const f32x4*)(X + (size_t)(mBase + r) * K_DIM + kBase + c);
            rb[cc] = *(const f32x4*)(W + (size_t)(nBase + r) * K_DIM + kBase + c);
        }
        __syncthreads();
        #pragma unroll
        for (int cc = 0; cc < 8; ++cc) {
            const int e = cc * 1024 + t * 4;
            u16x4 pa, pb;
            #pragma unroll
            for (int q = 0; q < 4; ++q) { pa[q] = f2bf(ra[cc][q]); pb[q] = f2bf(rb[cc][q]); }
            *(u16x4*)(smA + e) = pa;
            *(u16x4*)(smB + e) = pb;
        }
        __syncthreads();
        #pragma unroll
        for (int kk = 0; kk < FBK / 32; ++kk) {
            bf16x8 afr[4], bfr[4];
            #pragma unroll
            for (int i = 0; i < 4; ++i) {
                afr[i] = *(const bf16x8*)(smA + (wr * 64 + i * 16 + cl) * FBK + kk * 32 + rl * 8);
                bfr[i] = *(const bf16x8*)(smB + (wc * 64 + i * 16 + cl) * FBK + kk * 32 + rl * 8);
            }
            #pragma unroll
            for (int i = 0; i < 4; ++i)
                #pragma unroll
                for (int j = 0; j < 4; ++j)
                    acc[i][j] = __builtin_amdgcn_mfma_f32_16x16x32_bf16(
                        afr[i], bfr[j], acc[i][j], 0, 0, 0);
        }
    }
    #pragma unroll
    for (int j = 0; j < 4; ++j) {
        const int gn = nBase + wc * 64 + j * 16 + cl;
        const float swv = SW[gn], bv = BIAS[gn];
        #pragma unroll
        for (int i = 0; i < 4; ++i) {
            const int gmb = mBase + wr * 64 + i * 16 + rl * 4;
            #pragma unroll
            for (int r = 0; r < 4; ++r) {
                float v = acc[i][j][r] * SX[gmb + r] * swv + bv;
                v = fminf(fmaxf(v, -1.0e5f), 1.0e5f);
                OUT[(size_t)(gmb + r) * N_DIM + gn] = v;
            }
        }
    }
}

extern "C" void kernel_launch(void* const* d_in, const int* in_sizes, int n_in,
                              void* d_out, int out_size, void* d_ws, size_t ws_size,
                              hipStream_t stream) {
    const void* pX = d_in[0]; const void* pSX = d_in[1]; const void* pW = d_in[2];
    const void* pSW = d_in[3]; const void* pBS = d_in[4];
    for (int i = 0; i < n_in; ++i) {
        if (in_sizes[i] == M_DIM * K_DIM)      pX  = d_in[i];
        else if (in_sizes[i] == M_DIM)         pSX = d_in[i];
        else if (in_sizes[i] == N_DIM * K_DIM) pW  = d_in[i];
    }
    {
        int first = -1, second = -1;
        for (int i = 0; i < n_in; ++i)
            if (in_sizes[i] == N_DIM) { if (first < 0) first = i; else if (second < 0) second = i; }
        if (first >= 0)  pSW = d_in[first];
        if (second >= 0) pBS = d_in[second];
    }

    if (ws_size >= WS_NEEDED) {
        unsigned short* Xb = (unsigned short*)d_ws;
        unsigned short* Wb = Xb + X_ELEMS;
        convert_f32_to_bf16<<<2048, 256, 0, stream>>>((const float*)pX, Xb, X_ELEMS);
        convert_f32_to_bf16<<<2048, 256, 0, stream>>>((const float*)pW, Wb, W_ELEMS);
        linear_flh_gemm_256<<<dim3(NWG), 512, 0, stream>>>(
            Xb, Wb, (const float*)pSX, (const float*)pSW, (const float*)pBS,
            (float*)d_out);
    } else {
        dim3 grid((M_DIM / FBM) * (N_DIM / FBM));
        linear_flh_gemm_f32in<<<grid, 256, 0, stream>>>(
            (const float*)pX, (const float*)pSX, (const float*)pW,
            (const float*)pSW, (const float*)pBS, (float*)d_out);
    }
}